// Round 1
// baseline (221.749 us; speedup 1.0000x reference)
//
#include <hip/hip_runtime.h>
#include <hip/hip_bf16.h>

#define NPIX 9216

typedef __attribute__((ext_vector_type(4))) float f32x4;
typedef __attribute__((ext_vector_type(8))) short bf16x8;

// ---------------- Kernel 1: spectral norm sigmas (1 block, 64 threads) ------
__global__ void spectral_kernel(const float* __restrict__ Wf, const float* __restrict__ Wg,
                                const float* __restrict__ Wh, const float* __restrict__ uf,
                                const float* __restrict__ ug, const float* __restrict__ uh,
                                float* __restrict__ inv_sigma) {
  __shared__ float vsh[64];
  const int t = threadIdx.x;  // 0..63, one wave
  for (int widx = 0; widx < 3; ++widx) {
    const float* W = (widx == 0) ? Wf : (widx == 1) ? Wg : Wh;
    const float* u = (widx == 0) ? uf : (widx == 1) ? ug : uh;
    const int O = (widx == 2) ? 64 : 8;
    // v = W^T u  (length 64)
    float v = 0.f;
    for (int o = 0; o < O; ++o) v += W[o * 64 + t] * u[o];
    float s = v * v;
    for (int off = 32; off; off >>= 1) s += __shfl_xor(s, off);
    const float vn = v / (sqrtf(s) + 1e-12f);
    vsh[t] = vn;
    __syncthreads();
    // w = W v (length O); sigma = ||w||^2 / (||w|| + eps)
    float wv = 0.f;
    if (t < O) { for (int c = 0; c < 64; ++c) wv += W[t * 64 + c] * vsh[c]; }
    float s2 = (t < O) ? wv * wv : 0.f;
    for (int off = 32; off; off >>= 1) s2 += __shfl_xor(s2, off);
    const float nw = sqrtf(s2);
    const float sigma = s2 / (nw + 1e-12f);
    if (t == 0) inv_sigma[widx] = 1.f / sigma;
    __syncthreads();
  }
}

// ---------------- Kernel 2: f,g,h projections --------------------------------
// Q  : [NPIX][8]  f32   (f transposed)
// Kt : [8][NPIX]  f32   (g natural layout)
// Vt : [64][NPIX] bf16  (h natural layout)
__global__ __launch_bounds__(256) void fgh_kernel(
    const float* __restrict__ x,
    const float* __restrict__ Wf, const float* __restrict__ bf,
    const float* __restrict__ Wg, const float* __restrict__ bg,
    const float* __restrict__ Wh, const float* __restrict__ bh,
    const float* __restrict__ inv_sigma,
    float* __restrict__ Q, float* __restrict__ Kt, ushort* __restrict__ Vt) {
  const int p = blockIdx.x * 256 + threadIdx.x;   // pixel
  const int by = blockIdx.y;                      // rows 4*by .. 4*by+3 of 80
  const float* Wp[4]; const float* bp[4]; float isv[4]; int ro[4];
  #pragma unroll
  for (int rr = 0; rr < 4; ++rr) {
    const int r = by * 4 + rr;
    if (r < 8)       { Wp[rr] = Wf; bp[rr] = bf; isv[rr] = inv_sigma[0]; ro[rr] = r; }
    else if (r < 16) { Wp[rr] = Wg; bp[rr] = bg; isv[rr] = inv_sigma[1]; ro[rr] = r - 8; }
    else             { Wp[rr] = Wh; bp[rr] = bh; isv[rr] = inv_sigma[2]; ro[rr] = r - 16; }
  }
  float a[4] = {0.f, 0.f, 0.f, 0.f};
  for (int c = 0; c < 64; ++c) {
    const float xv = x[c * NPIX + p];
    #pragma unroll
    for (int rr = 0; rr < 4; ++rr) a[rr] += Wp[rr][ro[rr] * 64 + c] * xv;
  }
  #pragma unroll
  for (int rr = 0; rr < 4; ++rr) {
    const int r = by * 4 + rr;
    const float val = a[rr] * isv[rr] + bp[rr][ro[rr]];
    if (r < 8)       Q[p * 8 + r] = val;
    else if (r < 16) Kt[(r - 8) * NPIX + p] = val;
    else {
      __hip_bfloat16 hv = __float2bfloat16(val);
      Vt[(r - 16) * NPIX + p] = *(ushort*)&hv;
    }
  }
}

// ---------------- Kernel 3: fused flash attention ----------------------------
// Block: 16 query rows (m0..m0+15), 4 waves split n-range 4-way, LDS-merge.
// Per wave lane l: m = l&15, n-slot block g = l>>4; S computed by VALU directly
// in MFMA A-frag layout; P (bf16) x V (bf16) via mfma_f32_16x16x32_bf16.
__global__ __launch_bounds__(256) void attn_kernel(
    const float* __restrict__ Q, const float* __restrict__ Kt,
    const ushort* __restrict__ Vt, const float* __restrict__ x,
    const float* __restrict__ gammap, float* __restrict__ out) {
  __shared__ float O_s[4][16][65];  // +1 pad: conflict-free combine reads
  __shared__ float mx_s[4][16];
  __shared__ float ls_s[4][16];
  const int tid  = threadIdx.x;
  const int w    = tid >> 6;
  const int l    = tid & 63;
  const int mloc = l & 15;
  const int g    = l >> 4;
  const int m0   = blockIdx.x * 16;

  float q[8];
  {
    const f32x4* qp = (const f32x4*)(Q + (m0 + mloc) * 8);
    const f32x4 q0 = qp[0], q1 = qp[1];
    q[0] = q0[0]; q[1] = q0[1]; q[2] = q0[2]; q[3] = q0[3];
    q[4] = q1[0]; q[5] = q1[1]; q[6] = q1[2]; q[7] = q1[3];
  }
  float mx = -INFINITY, ls = 0.f;
  f32x4 acc0 = {0.f, 0.f, 0.f, 0.f}, acc1 = acc0, acc2 = acc0, acc3 = acc0;
  const int n_begin = w * (NPIX / 4);

  for (int it = 0; it < (NPIX / 4) / 32; ++it) {
    const int nb = n_begin + it * 32 + g * 8;  // this lane's 8 n's
    float sj[8] = {0.f, 0.f, 0.f, 0.f, 0.f, 0.f, 0.f, 0.f};
    #pragma unroll
    for (int k = 0; k < 8; ++k) {
      const f32x4* kp = (const f32x4*)(Kt + k * NPIX + nb);
      const f32x4 ka = kp[0], kb = kp[1];
      sj[0] += q[k] * ka[0]; sj[1] += q[k] * ka[1];
      sj[2] += q[k] * ka[2]; sj[3] += q[k] * ka[3];
      sj[4] += q[k] * kb[0]; sj[5] += q[k] * kb[1];
      sj[6] += q[k] * kb[2]; sj[7] += q[k] * kb[3];
    }
    // row-tile max (reduce over j in-lane, then over g groups)
    float tm = sj[0];
    #pragma unroll
    for (int j = 1; j < 8; ++j) tm = fmaxf(tm, sj[j]);
    tm = fmaxf(tm, __shfl_xor(tm, 16));
    tm = fmaxf(tm, __shfl_xor(tm, 32));
    const float mxn = fmaxf(mx, tm);
    if (__any(tm > mx)) {  // rescale path (rare after first tiles)
      const float corr = __expf(mx - mxn);
      ls *= corr;
      // broadcast corr of row (g*4+i) to C-frag layout
      const float c0 = __shfl(corr, (g << 2) + 0);
      const float c1 = __shfl(corr, (g << 2) + 1);
      const float c2 = __shfl(corr, (g << 2) + 2);
      const float c3 = __shfl(corr, (g << 2) + 3);
      acc0[0] *= c0; acc0[1] *= c1; acc0[2] *= c2; acc0[3] *= c3;
      acc1[0] *= c0; acc1[1] *= c1; acc1[2] *= c2; acc1[3] *= c3;
      acc2[0] *= c0; acc2[1] *= c1; acc2[2] *= c2; acc2[3] *= c3;
      acc3[0] *= c0; acc3[1] *= c1; acc3[2] *= c2; acc3[3] *= c3;
      mx = mxn;
    }
    float pj[8]; float ps = 0.f;
    #pragma unroll
    for (int j = 0; j < 8; ++j) { pj[j] = __expf(sj[j] - mxn); ps += pj[j]; }
    ps += __shfl_xor(ps, 16);
    ps += __shfl_xor(ps, 32);
    ls += ps;
    // pack P to bf16 A-frag (elem order == n order, matches V B-frag)
    union { unsigned int u[4]; bf16x8 v; } pu;
    #pragma unroll
    for (int j = 0; j < 4; ++j) {
      unsigned int r;
      asm("v_cvt_pk_bf16_f32 %0, %1, %2" : "=v"(r) : "v"(pj[2 * j]), "v"(pj[2 * j + 1]));
      pu.u[j] = r;
    }
    const bf16x8 v0 = *(const bf16x8*)(Vt + (mloc)      * NPIX + nb);
    const bf16x8 v1 = *(const bf16x8*)(Vt + (16 + mloc) * NPIX + nb);
    const bf16x8 v2 = *(const bf16x8*)(Vt + (32 + mloc) * NPIX + nb);
    const bf16x8 v3 = *(const bf16x8*)(Vt + (48 + mloc) * NPIX + nb);
    acc0 = __builtin_amdgcn_mfma_f32_16x16x32_bf16(pu.v, v0, acc0, 0, 0, 0);
    acc1 = __builtin_amdgcn_mfma_f32_16x16x32_bf16(pu.v, v1, acc1, 0, 0, 0);
    acc2 = __builtin_amdgcn_mfma_f32_16x16x32_bf16(pu.v, v2, acc2, 0, 0, 0);
    acc3 = __builtin_amdgcn_mfma_f32_16x16x32_bf16(pu.v, v3, acc3, 0, 0, 0);
  }

  if (l < 16) { mx_s[w][l] = mx; ls_s[w][l] = ls; }
  #pragma unroll
  for (int i = 0; i < 4; ++i) {
    const int r = g * 4 + i;  // C-frag row
    O_s[w][r][mloc]      = acc0[i];
    O_s[w][r][16 + mloc] = acc1[i];
    O_s[w][r][32 + mloc] = acc2[i];
    O_s[w][r][48 + mloc] = acc3[i];
  }
  __syncthreads();
  const float gamma = gammap[0];
  #pragma unroll
  for (int e = tid; e < 1024; e += 256) {
    const int m = e & 15, c = e >> 4;  // consecutive tid -> consecutive m (coalesced out)
    const float ma = mx_s[0][m], mb = mx_s[1][m], mc = mx_s[2][m], md = mx_s[3][m];
    const float M = fmaxf(fmaxf(ma, mb), fmaxf(mc, md));
    const float e0 = __expf(ma - M), e1 = __expf(mb - M), e2 = __expf(mc - M), e3 = __expf(md - M);
    const float L = ls_s[0][m] * e0 + ls_s[1][m] * e1 + ls_s[2][m] * e2 + ls_s[3][m] * e3;
    const float val = O_s[0][m][c] * e0 + O_s[1][m][c] * e1 + O_s[2][m][c] * e2 + O_s[3][m][c] * e3;
    const int idx = c * NPIX + m0 + m;
    out[idx] = gamma * (val / L) + x[idx];
  }
}

// ---------------- launcher ---------------------------------------------------
extern "C" void kernel_launch(void* const* d_in, const int* in_sizes, int n_in,
                              void* d_out, int out_size, void* d_ws, size_t ws_size,
                              hipStream_t stream) {
  const float* x     = (const float*)d_in[0];
  const float* Wf    = (const float*)d_in[1];
  const float* bf    = (const float*)d_in[2];
  const float* Wg    = (const float*)d_in[3];
  const float* bg    = (const float*)d_in[4];
  const float* Wh    = (const float*)d_in[5];
  const float* bh    = (const float*)d_in[6];
  const float* gamma = (const float*)d_in[7];
  const float* uf    = (const float*)d_in[8];
  const float* ug    = (const float*)d_in[9];
  const float* uh    = (const float*)d_in[10];
  float* out = (float*)d_out;

  char* ws = (char*)d_ws;
  float*  inv_sigma = (float*)ws;                                  // 12 B
  float*  Q  = (float*)(ws + 256);                                 // 294912 B
  float*  Kt = (float*)(ws + 256 + NPIX * 8 * 4);                  // 294912 B
  ushort* Vt = (ushort*)(ws + 256 + 2 * NPIX * 8 * 4);             // 1179648 B

  spectral_kernel<<<1, 64, 0, stream>>>(Wf, Wg, Wh, uf, ug, uh, inv_sigma);
  fgh_kernel<<<dim3(NPIX / 256, 20), 256, 0, stream>>>(x, Wf, bf, Wg, bg, Wh, bh,
                                                       inv_sigma, Q, Kt, Vt);
  attn_kernel<<<NPIX / 16, 256, 0, stream>>>(Q, Kt, Vt, x, gamma, out);
}

// Round 2
// 190.268 us; speedup vs baseline: 1.1655x; 1.1655x over previous
//
#include <hip/hip_runtime.h>
#include <hip/hip_bf16.h>

#define NPIX 9216
#define SPLIT 4
#define MTILES (NPIX / 16)          // 576
#define NB_PER_BLOCK (NPIX / SPLIT) // 2304
#define NB_PER_WAVE (NB_PER_BLOCK / 4) // 576
#define TILES_PER_WAVE (NB_PER_WAVE / 32) // 18

typedef __attribute__((ext_vector_type(4))) float f32x4;
typedef __attribute__((ext_vector_type(8))) short bf16x8;

// ---------------- Kernel 1: spectral norm sigmas (1 block, 64 threads) ------
__global__ void spectral_kernel(const float* __restrict__ Wf, const float* __restrict__ Wg,
                                const float* __restrict__ Wh, const float* __restrict__ uf,
                                const float* __restrict__ ug, const float* __restrict__ uh,
                                float* __restrict__ inv_sigma) {
  __shared__ float vsh[64];
  const int t = threadIdx.x;  // 0..63, one wave
  for (int widx = 0; widx < 3; ++widx) {
    const float* W = (widx == 0) ? Wf : (widx == 1) ? Wg : Wh;
    const float* u = (widx == 0) ? uf : (widx == 1) ? ug : uh;
    const int O = (widx == 2) ? 64 : 8;
    // v = W^T u  (length 64)
    float v = 0.f;
    for (int o = 0; o < O; ++o) v += W[o * 64 + t] * u[o];
    float s = v * v;
    for (int off = 32; off; off >>= 1) s += __shfl_xor(s, off);
    const float vn = v / (sqrtf(s) + 1e-12f);
    vsh[t] = vn;
    __syncthreads();
    // w = W v (length O); sigma = ||w||^2 / (||w|| + eps)
    float wv = 0.f;
    if (t < O) { for (int c = 0; c < 64; ++c) wv += W[t * 64 + c] * vsh[c]; }
    float s2 = (t < O) ? wv * wv : 0.f;
    for (int off = 32; off; off >>= 1) s2 += __shfl_xor(s2, off);
    const float nw = sqrtf(s2);
    const float sigma = s2 / (nw + 1e-12f);
    if (t == 0) inv_sigma[widx] = 1.f / sigma;
    __syncthreads();
  }
}

// ---------------- Kernel 2: f,g,h projections --------------------------------
// Q  : [NPIX][8]  f32   (f transposed)
// Kt : [8][NPIX]  f32   (g natural layout)
// Vt : [64][NPIX] bf16  (h natural layout)
__global__ __launch_bounds__(256) void fgh_kernel(
    const float* __restrict__ x,
    const float* __restrict__ Wf, const float* __restrict__ bf,
    const float* __restrict__ Wg, const float* __restrict__ bg,
    const float* __restrict__ Wh, const float* __restrict__ bh,
    const float* __restrict__ inv_sigma,
    float* __restrict__ Q, float* __restrict__ Kt, ushort* __restrict__ Vt) {
  const int p = blockIdx.x * 256 + threadIdx.x;   // pixel
  const int by = blockIdx.y;                      // rows 4*by .. 4*by+3 of 80
  const float* Wp[4]; const float* bp[4]; float isv[4]; int ro[4];
  #pragma unroll
  for (int rr = 0; rr < 4; ++rr) {
    const int r = by * 4 + rr;
    if (r < 8)       { Wp[rr] = Wf; bp[rr] = bf; isv[rr] = inv_sigma[0]; ro[rr] = r; }
    else if (r < 16) { Wp[rr] = Wg; bp[rr] = bg; isv[rr] = inv_sigma[1]; ro[rr] = r - 8; }
    else             { Wp[rr] = Wh; bp[rr] = bh; isv[rr] = inv_sigma[2]; ro[rr] = r - 16; }
  }
  float a[4] = {0.f, 0.f, 0.f, 0.f};
  for (int c = 0; c < 64; ++c) {
    const float xv = x[c * NPIX + p];
    #pragma unroll
    for (int rr = 0; rr < 4; ++rr) a[rr] += Wp[rr][ro[rr] * 64 + c] * xv;
  }
  #pragma unroll
  for (int rr = 0; rr < 4; ++rr) {
    const int r = by * 4 + rr;
    const float val = a[rr] * isv[rr] + bp[rr][ro[rr]];
    if (r < 8)       Q[p * 8 + r] = val;
    else if (r < 16) Kt[(r - 8) * NPIX + p] = val;
    else {
      __hip_bfloat16 hv = __float2bfloat16(val);
      Vt[(r - 16) * NPIX + p] = *(ushort*)&hv;
    }
  }
}

// ---------------- Kernel 3a: flash attention, split-n partials ---------------
// Grid: (MTILES, SPLIT). Block: 16 query rows, 4 waves split the block's
// n-range 4-way, merge via LDS, write UN-normalized partial (O, m, l) to ws.
__global__ __launch_bounds__(256) void attn_kernel(
    const float* __restrict__ Q, const float* __restrict__ Kt,
    const ushort* __restrict__ Vt,
    float* __restrict__ Om,   // [MTILES][SPLIT][1024]  (e = c*16+m)
    float* __restrict__ Sm) { // [MTILES][SPLIT][32]    (16 mx, 16 ls)
  __shared__ float O_s[4][16][65];
  __shared__ float mx_s[4][16];
  __shared__ float ls_s[4][16];
  const int tid  = threadIdx.x;
  const int w    = tid >> 6;
  const int l    = tid & 63;
  const int mloc = l & 15;
  const int g    = l >> 4;
  const int m0   = blockIdx.x * 16;
  const int spl  = blockIdx.y;

  float q[8];
  {
    const f32x4* qp = (const f32x4*)(Q + (m0 + mloc) * 8);
    const f32x4 q0 = qp[0], q1 = qp[1];
    q[0] = q0[0]; q[1] = q0[1]; q[2] = q0[2]; q[3] = q0[3];
    q[4] = q1[0]; q[5] = q1[1]; q[6] = q1[2]; q[7] = q1[3];
  }
  float mx = -INFINITY, ls = 0.f;
  f32x4 acc0 = {0.f, 0.f, 0.f, 0.f}, acc1 = acc0, acc2 = acc0, acc3 = acc0;
  const int n_begin = spl * NB_PER_BLOCK + w * NB_PER_WAVE;

  for (int it = 0; it < TILES_PER_WAVE; ++it) {
    const int nb = n_begin + it * 32 + g * 8;  // this lane's 8 n's
    float sj[8] = {0.f, 0.f, 0.f, 0.f, 0.f, 0.f, 0.f, 0.f};
    #pragma unroll
    for (int k = 0; k < 8; ++k) {
      const f32x4* kp = (const f32x4*)(Kt + k * NPIX + nb);
      const f32x4 ka = kp[0], kb = kp[1];
      sj[0] += q[k] * ka[0]; sj[1] += q[k] * ka[1];
      sj[2] += q[k] * ka[2]; sj[3] += q[k] * ka[3];
      sj[4] += q[k] * kb[0]; sj[5] += q[k] * kb[1];
      sj[6] += q[k] * kb[2]; sj[7] += q[k] * kb[3];
    }
    // row-tile max (reduce over j in-lane, then over g groups)
    float tm = sj[0];
    #pragma unroll
    for (int j = 1; j < 8; ++j) tm = fmaxf(tm, sj[j]);
    tm = fmaxf(tm, __shfl_xor(tm, 16));
    tm = fmaxf(tm, __shfl_xor(tm, 32));
    const float mxn = fmaxf(mx, tm);
    if (__any(tm > mx)) {  // rescale path (rare after first tiles)
      const float corr = __expf(mx - mxn);
      ls *= corr;
      const float c0 = __shfl(corr, (g << 2) + 0);
      const float c1 = __shfl(corr, (g << 2) + 1);
      const float c2 = __shfl(corr, (g << 2) + 2);
      const float c3 = __shfl(corr, (g << 2) + 3);
      acc0[0] *= c0; acc0[1] *= c1; acc0[2] *= c2; acc0[3] *= c3;
      acc1[0] *= c0; acc1[1] *= c1; acc1[2] *= c2; acc1[3] *= c3;
      acc2[0] *= c0; acc2[1] *= c1; acc2[2] *= c2; acc2[3] *= c3;
      acc3[0] *= c0; acc3[1] *= c1; acc3[2] *= c2; acc3[3] *= c3;
      mx = mxn;
    }
    float pj[8]; float ps = 0.f;
    #pragma unroll
    for (int j = 0; j < 8; ++j) { pj[j] = __expf(sj[j] - mxn); ps += pj[j]; }
    ps += __shfl_xor(ps, 16);
    ps += __shfl_xor(ps, 32);
    ls += ps;
    // pack P to bf16 A-frag (elem order == n order, matches V B-frag)
    union { unsigned int u[4]; bf16x8 v; } pu;
    #pragma unroll
    for (int j = 0; j < 4; ++j) {
      unsigned int r;
      asm("v_cvt_pk_bf16_f32 %0, %1, %2" : "=v"(r) : "v"(pj[2 * j]), "v"(pj[2 * j + 1]));
      pu.u[j] = r;
    }
    const bf16x8 v0 = *(const bf16x8*)(Vt + (mloc)      * NPIX + nb);
    const bf16x8 v1 = *(const bf16x8*)(Vt + (16 + mloc) * NPIX + nb);
    const bf16x8 v2 = *(const bf16x8*)(Vt + (32 + mloc) * NPIX + nb);
    const bf16x8 v3 = *(const bf16x8*)(Vt + (48 + mloc) * NPIX + nb);
    acc0 = __builtin_amdgcn_mfma_f32_16x16x32_bf16(pu.v, v0, acc0, 0, 0, 0);
    acc1 = __builtin_amdgcn_mfma_f32_16x16x32_bf16(pu.v, v1, acc1, 0, 0, 0);
    acc2 = __builtin_amdgcn_mfma_f32_16x16x32_bf16(pu.v, v2, acc2, 0, 0, 0);
    acc3 = __builtin_amdgcn_mfma_f32_16x16x32_bf16(pu.v, v3, acc3, 0, 0, 0);
  }

  if (l < 16) { mx_s[w][l] = mx; ls_s[w][l] = ls; }
  #pragma unroll
  for (int i = 0; i < 4; ++i) {
    const int r = g * 4 + i;  // C-frag row
    O_s[w][r][mloc]      = acc0[i];
    O_s[w][r][16 + mloc] = acc1[i];
    O_s[w][r][32 + mloc] = acc2[i];
    O_s[w][r][48 + mloc] = acc3[i];
  }
  __syncthreads();
  // merge 4 waves -> un-normalized partial for this split
  float* Ob = Om + (blockIdx.x * SPLIT + spl) * 1024;
  float* Sb = Sm + (blockIdx.x * SPLIT + spl) * 32;
  #pragma unroll
  for (int e = tid; e < 1024; e += 256) {
    const int m = e & 15, c = e >> 4;
    const float ma = mx_s[0][m], mb = mx_s[1][m], mc = mx_s[2][m], md = mx_s[3][m];
    const float M = fmaxf(fmaxf(ma, mb), fmaxf(mc, md));
    const float e0 = __expf(ma - M), e1 = __expf(mb - M), e2 = __expf(mc - M), e3 = __expf(md - M);
    const float L = ls_s[0][m] * e0 + ls_s[1][m] * e1 + ls_s[2][m] * e2 + ls_s[3][m] * e3;
    const float val = O_s[0][m][c] * e0 + O_s[1][m][c] * e1 + O_s[2][m][c] * e2 + O_s[3][m][c] * e3;
    Ob[e] = val;
    if (e < 16)       Sb[e] = M;        // mx for row e
    else if (e < 32)  Sb[e] = ls_s[0][e - 16] * __expf(mx_s[0][e - 16] - Sb[e - 16]);
  }
  // NOTE: L must be written, not recomputed partially — write ls properly:
  if (tid < 16) {
    const int m = tid;
    const float ma = mx_s[0][m], mb = mx_s[1][m], mc = mx_s[2][m], md = mx_s[3][m];
    const float M = fmaxf(fmaxf(ma, mb), fmaxf(mc, md));
    const float L = ls_s[0][m] * __expf(ma - M) + ls_s[1][m] * __expf(mb - M)
                  + ls_s[2][m] * __expf(mc - M) + ls_s[3][m] * __expf(md - M);
    Sb[m]      = M;
    Sb[16 + m] = L;
  }
}

// ---------------- Kernel 3b: combine split partials --------------------------
__global__ __launch_bounds__(256) void combine_kernel(
    const float* __restrict__ Om, const float* __restrict__ Sm,
    const float* __restrict__ x, const float* __restrict__ gammap,
    float* __restrict__ out) {
  const int mt = blockIdx.x;
  const int m0 = mt * 16;
  const float gamma = gammap[0];
  const float* Sb = Sm + mt * SPLIT * 32;
  const float* Ob = Om + mt * SPLIT * 1024;
  #pragma unroll
  for (int e = threadIdx.x; e < 1024; e += 256) {
    const int m = e & 15, c = e >> 4;
    float M = -INFINITY;
    #pragma unroll
    for (int s = 0; s < SPLIT; ++s) M = fmaxf(M, Sb[s * 32 + m]);
    float L = 0.f, val = 0.f;
    #pragma unroll
    for (int s = 0; s < SPLIT; ++s) {
      const float ws = __expf(Sb[s * 32 + m] - M);
      L   += Sb[s * 32 + 16 + m] * ws;
      val += Ob[s * 1024 + e] * ws;
    }
    const int idx = c * NPIX + m0 + m;
    out[idx] = gamma * (val / L) + x[idx];
  }
}

// ---------------- launcher ---------------------------------------------------
extern "C" void kernel_launch(void* const* d_in, const int* in_sizes, int n_in,
                              void* d_out, int out_size, void* d_ws, size_t ws_size,
                              hipStream_t stream) {
  const float* x     = (const float*)d_in[0];
  const float* Wf    = (const float*)d_in[1];
  const float* bf    = (const float*)d_in[2];
  const float* Wg    = (const float*)d_in[3];
  const float* bg    = (const float*)d_in[4];
  const float* Wh    = (const float*)d_in[5];
  const float* bh    = (const float*)d_in[6];
  const float* gamma = (const float*)d_in[7];
  const float* uf    = (const float*)d_in[8];
  const float* ug    = (const float*)d_in[9];
  const float* uh    = (const float*)d_in[10];
  float* out = (float*)d_out;

  char* ws = (char*)d_ws;
  float*  inv_sigma = (float*)ws;                                  // 12 B
  float*  Q  = (float*)(ws + 256);                                 // 294912 B
  float*  Kt = (float*)(ws + 256 + NPIX * 8 * 4);                  // 294912 B
  ushort* Vt = (ushort*)(ws + 256 + 2 * NPIX * 8 * 4);             // 1179648 B
  size_t off = 256 + (size_t)2 * NPIX * 8 * 4 + (size_t)NPIX * 64 * 2;
  float* Om = (float*)(ws + off);                                  // 9437184 B
  float* Sm = (float*)(ws + off + (size_t)MTILES * SPLIT * 1024 * 4); // 294912 B

  spectral_kernel<<<1, 64, 0, stream>>>(Wf, Wg, Wh, uf, ug, uh, inv_sigma);
  fgh_kernel<<<dim3(NPIX / 256, 20), 256, 0, stream>>>(x, Wf, bf, Wg, bg, Wh, bh,
                                                       inv_sigma, Q, Kt, Vt);
  attn_kernel<<<dim3(MTILES, SPLIT), 256, 0, stream>>>(Q, Kt, Vt, Om, Sm);
  combine_kernel<<<MTILES, 256, 0, stream>>>(Om, Sm, x, gamma, out);
}